// Round 1
// baseline (37303.961 us; speedup 1.0000x reference)
//
#include <hip/hip_runtime.h>
#include <hip/hip_bf16.h>
#include <math.h>

#define T_STEPS 2048
#define N_MOD   64
#define N_HID   256
#define N_INP   128

#define AG_LD(p)      __hip_atomic_load((p),  __ATOMIC_RELAXED, __HIP_MEMORY_SCOPE_AGENT)
#define AG_LD_ACQ(p)  __hip_atomic_load((p),  __ATOMIC_ACQUIRE, __HIP_MEMORY_SCOPE_AGENT)
#define AG_ST(p, v)   __hip_atomic_store((p), (v), __ATOMIC_RELAXED, __HIP_MEMORY_SCOPE_AGENT)
#define AG_ST_REL(p, v) __hip_atomic_store((p), (v), __ATOMIC_RELEASE, __HIP_MEMORY_SCOPE_AGENT)

// --------------------------------------------------------------------------
// Pre-pass: xpre[t,n,h] = sum_i x2h[n,h,i] * x[t,i]
// Written into the fb_seq region of d_out (identical size); the persistent
// kernel reads xpre[t] and then overwrites it with fb[t] (same thread, read
// before write -> deterministic across graph replays).
// --------------------------------------------------------------------------
__global__ __launch_bounds__(256) void xpre_kernel(
    const float* __restrict__ x, const float* __restrict__ x2h,
    float* __restrict__ out)
{
  __shared__ float xl[64 * N_INP];           // 32 KB: 64 timesteps of x
  const int tb = blockIdx.x;                  // timestep block (64 steps)
  const int n  = blockIdx.y;                  // module
  const int t  = threadIdx.x;                 // h index 0..255

  const float4* xs  = (const float4*)(x + (size_t)tb * 64 * N_INP);
  float4*       xld = (float4*)xl;
  for (int k = t; k < 64 * N_INP / 4; k += 256) xld[k] = xs[k];

  float w[N_INP];                             // x2h[n, h=t, :] in VGPRs
  const float* wrow = x2h + ((size_t)n * N_HID + t) * N_INP;
#pragma unroll
  for (int j = 0; j < N_INP; j += 4) {
    const float4 a = *(const float4*)(wrow + j);
    w[j] = a.x; w[j+1] = a.y; w[j+2] = a.z; w[j+3] = a.w;
  }
  __syncthreads();

  for (int tt = 0; tt < 64; ++tt) {
    float a0=0.f, a1=0.f, a2=0.f, a3=0.f;
#pragma unroll
    for (int j = 0; j < N_INP; j += 4) {
      const float4 h4 = *(const float4*)&xl[tt * N_INP + j];
      a0 = fmaf(w[j],   h4.x, a0);
      a1 = fmaf(w[j+1], h4.y, a1);
      a2 = fmaf(w[j+2], h4.z, a2);
      a3 = fmaf(w[j+3], h4.w, a3);
    }
    out[((size_t)(tb*64 + tt) * N_MOD + n) * N_HID + t] = (a0+a1)+(a2+a3);
  }
}

// --------------------------------------------------------------------------
// Persistent stepping kernel.
// 128 WGs x 512 threads. WG w: module m = w>>1, half p = w&1 owns output
// rows h in [p*128, p*128+128). Thread t: hi = t&127 (row), c = t>>7 (one of
// 4 column chunks of 64). Weights h2h[m, hrow, c*64:+64] and
// wm[hrow, c*64:+64] live in VGPRs for the whole run.
//
// Per step s:
//   s>0 : v[m,hrow] = wm[hrow,:].hy[m,:]  (local)  -> publish (agent/sc1)
//         r partials (overlaps remote publishes)   -> flag_v[w] = s (release)
//         wait all flags_v >= s -> fb[m,hrow] = sum_m' conn[m,m'] v[m',hrow]
//   s==0: fb = 0 exactly (reference uses outs0 = zeros); r only.
//   update: pre = xpre + r + bias + fb; tanh; semi-implicit Euler;
//   write states_seq[s+1], fb_seq[s]; publish hy half -> sibling exchange.
// vbuf double-buffered by (s&1); flag protocol bounds skew to 1 step.
// --------------------------------------------------------------------------
__global__ __launch_bounds__(512) void archnet_step(
    const float* __restrict__ init, const float* __restrict__ wm,
    const float* __restrict__ conn, const float* __restrict__ h2h,
    const float* __restrict__ bias,
    float* __restrict__ out_states, float* __restrict__ out_fb,
    float* vbuf, float* hybuf, unsigned* flags_v, unsigned* flags_h)
{
  const int w  = blockIdx.x;        // 0..127
  const int m  = w >> 1;
  const int p  = w & 1;
  const int t  = threadIdx.x;       // 0..511
  const int hi = t & 127;
  const int c  = t >> 7;            // 0..3
  const int hrow = p * 128 + hi;    // owned output row

  __shared__ float hy[N_HID];       // full hy[m,:]
  __shared__ float redv[512];
  __shared__ float redr[512];
  __shared__ float connrow[N_MOD];

  // ---- resident weights ----
  float wh[64], wv[64];
  {
    const float* hp = h2h + ((size_t)m * N_HID + hrow) * N_HID + c * 64;
    const float* wp = wm  + (size_t)hrow * N_HID + c * 64;
#pragma unroll
    for (int j = 0; j < 64; j += 4) {
      const float4 a = *(const float4*)(hp + j);
      wh[j] = a.x; wh[j+1] = a.y; wh[j+2] = a.z; wh[j+3] = a.w;
      const float4 b = *(const float4*)(wp + j);
      wv[j] = b.x; wv[j+1] = b.y; wv[j+2] = b.z; wv[j+3] = b.w;
    }
  }

  // ---- init state ----
  float biasv = 0.f, hzv = 0.f;
  if (t < N_HID) hy[t] = init[(size_t)m * 512 + t];      // initial_states[m,0,:]
  if (t < 128) {
    biasv = bias[(size_t)m * N_HID + hrow];
    hzv   = init[(size_t)m * 512 + 256 + hrow];          // initial_states[m,1,h]
    // states_seq[0] = initial_states
    out_states[(size_t)m * 512 + hrow]       = init[(size_t)m * 512 + hrow];
    out_states[(size_t)m * 512 + 256 + hrow] = hzv;
  }
  if (t < N_MOD) connrow[t] = conn[m * N_MOD + t];
  __syncthreads();

  for (int s = 0; s < T_STEPS; ++s) {
    float xq = 0.f;
    if (t < 128) xq = out_fb[((size_t)s * N_MOD + m) * N_HID + hrow];  // xpre
    float fb = 0.f;
    float* vb = vbuf + (size_t)(s & 1) * (N_MOD * N_HID);

    if (s > 0) {
      // v partial: wm[hrow,:] . hy  over column chunk c
      float a0=0.f, a1=0.f, a2=0.f, a3=0.f;
#pragma unroll
      for (int j = 0; j < 64; j += 4) {
        const float4 h4 = *(const float4*)&hy[c*64 + j];
        a0 = fmaf(wv[j],   h4.x, a0);
        a1 = fmaf(wv[j+1], h4.y, a1);
        a2 = fmaf(wv[j+2], h4.z, a2);
        a3 = fmaf(wv[j+3], h4.w, a3);
      }
      redv[t] = (a0+a1)+(a2+a3);
      __syncthreads();
      if (t < 128) {
        const float v = (redv[hi] + redv[hi+128]) + (redv[hi+256] + redv[hi+384]);
        AG_ST(&vb[m * N_HID + hrow], v);     // publish early
      }
    }

    // r partial: h2h[m,hrow,:] . hy  over column chunk c (overlaps publishes)
    {
      float b0=0.f, b1=0.f, b2=0.f, b3=0.f;
#pragma unroll
      for (int j = 0; j < 64; j += 4) {
        const float4 h4 = *(const float4*)&hy[c*64 + j];
        b0 = fmaf(wh[j],   h4.x, b0);
        b1 = fmaf(wh[j+1], h4.y, b1);
        b2 = fmaf(wh[j+2], h4.z, b2);
        b3 = fmaf(wh[j+3], h4.w, b3);
      }
      redr[t] = (b0+b1)+(b2+b3);
      __syncthreads();   // drains v publishes of all waves (vmcnt=0 at barrier)
    }

    if (s > 0) {
      if (t == 0) AG_ST_REL(&flags_v[w], (unsigned)s);
      if (t < 128) {
        while (AG_LD_ACQ(&flags_v[t]) < (unsigned)s) { }   // wait all 128 WGs
        // gather: fb[m,hrow] = sum_m' conn[m,m'] * v[m',hrow]
        float f0=0.f, f1=0.f, f2=0.f, f3=0.f;
#pragma unroll
        for (int mp = 0; mp < N_MOD; mp += 4) {
          const float v0 = AG_LD(&vb[(size_t)(mp+0) * N_HID + hrow]);
          const float v1 = AG_LD(&vb[(size_t)(mp+1) * N_HID + hrow]);
          const float v2 = AG_LD(&vb[(size_t)(mp+2) * N_HID + hrow]);
          const float v3 = AG_LD(&vb[(size_t)(mp+3) * N_HID + hrow]);
          f0 = fmaf(connrow[mp+0], v0, f0);
          f1 = fmaf(connrow[mp+1], v1, f1);
          f2 = fmaf(connrow[mp+2], v2, f2);
          f3 = fmaf(connrow[mp+3], v3, f3);
        }
        fb = (f0+f1)+(f2+f3);
      }
    }

    // ---- update (rows owned by this WG) ----
    if (t < 128) {
      const float r   = (redr[hi] + redr[hi+128]) + (redr[hi+256] + redr[hi+384]);
      const float pre = xq + r + biasv + fb;
      const float th  = tanhf(pre);
      const float hyo = hy[hrow];
      const float hzn = hzv + 0.01f * (th - hyo - hzv);   // GAMMA=EPS=1, DT=0.01
      const float hyn = hyo + 0.01f * hzn;
      hzv = hzn;
      const size_t ob = ((size_t)(s+1) * N_MOD + m) * 512;
      out_states[ob + hrow]       = hyn;
      out_states[ob + 256 + hrow] = hzn;
      out_fb[((size_t)s * N_MOD + m) * N_HID + hrow] = fb;  // overwrite xpre
      AG_ST(&hybuf[m * N_HID + hrow], hyn);                 // publish to sibling
      hy[hrow] = hyn;
    }
    __syncthreads();   // drains hybuf publishes before flag
    if (t == 0) AG_ST_REL(&flags_h[w], (unsigned)(s + 1));

    // ---- sibling exchange: fetch the other half of hy ----
    {
      const int sw = w ^ 1;
      if (t < 128) {
        while (AG_LD_ACQ(&flags_h[sw]) < (unsigned)(s + 1)) { }
        hy[(1 - p) * 128 + hi] = AG_LD(&hybuf[m * N_HID + (1 - p) * 128 + hi]);
      }
      __syncthreads();
    }
  }
}

// --------------------------------------------------------------------------
extern "C" void kernel_launch(void* const* d_in, const int* in_sizes, int n_in,
                              void* d_out, int out_size, void* d_ws, size_t ws_size,
                              hipStream_t stream) {
  const float* x    = (const float*)d_in[0];   // (2048,128)
  const float* init = (const float*)d_in[1];   // (64,2,256)
  const float* wmw  = (const float*)d_in[2];   // (256,256)
  const float* conn = (const float*)d_in[3];   // (64,64)
  const float* x2h  = (const float*)d_in[4];   // (64,256,128)
  const float* h2h  = (const float*)d_in[5];   // (64,256,256)
  const float* bias = (const float*)d_in[6];   // (64,256)

  float* out_states = (float*)d_out;                                   // (2049,64,2,256)
  float* out_fb     = out_states + (size_t)(T_STEPS+1) * N_MOD * 2 * N_HID; // (2048,64,256)

  // workspace: v double-buffer | hy sibling buffer | flags
  float*    vbuf    = (float*)d_ws;                         // 2*64*256
  float*    hybuf   = vbuf + 2 * N_MOD * N_HID;             // 64*256
  unsigned* flags_v = (unsigned*)(hybuf + N_MOD * N_HID);   // 128
  unsigned* flags_h = flags_v + 128;                        // 128
  const size_t ws_used = (size_t)(2*N_MOD*N_HID + N_MOD*N_HID) * 4 + 256 * 4;
  hipMemsetAsync(d_ws, 0, ws_used, stream);   // flags must start at 0 each call

  // Pre-pass: xpre into the fb_seq region of d_out.
  xpre_kernel<<<dim3(T_STEPS/64, N_MOD), dim3(256), 0, stream>>>(x, x2h, out_fb);

  // Persistent cooperative stepping kernel (co-residency guaranteed).
  void* args[] = {
    (void*)&init, (void*)&wmw, (void*)&conn, (void*)&h2h, (void*)&bias,
    (void*)&out_states, (void*)&out_fb,
    (void*)&vbuf, (void*)&hybuf, (void*)&flags_v, (void*)&flags_h
  };
  hipLaunchCooperativeKernel((void*)archnet_step, dim3(128), dim3(512),
                             args, 0, stream);
}

// Round 2
// 31796.231 us; speedup vs baseline: 1.1732x; 1.1732x over previous
//
#include <hip/hip_runtime.h>
#include <hip/hip_bf16.h>
#include <math.h>

#define T_STEPS 2048
#define N_MOD   64
#define N_HID   256
#define N_INP   128

// Relaxed agent-scope atomics (sc1 — coherent across XCDs, no per-op invalidate)
#define AG_LD(p)        __hip_atomic_load((p),  __ATOMIC_RELAXED, __HIP_MEMORY_SCOPE_AGENT)
#define AG_ST(p, v)     __hip_atomic_store((p), (v), __ATOMIC_RELAXED, __HIP_MEMORY_SCOPE_AGENT)
#define AG_ST_REL(p, v) __hip_atomic_store((p), (v), __ATOMIC_RELEASE, __HIP_MEMORY_SCOPE_AGENT)

// --------------------------------------------------------------------------
// Pre-pass: xpre[t,n,h] = sum_i x2h[n,h,i] * x[t,i], written into the fb_seq
// region of d_out. The stepping kernel reads xpre[t] then overwrites it with
// fb[t] (same thread, read-before-write -> deterministic across replays).
// launch_bounds(256,2): VGPR cap 256 so w[128] stays register-resident.
// --------------------------------------------------------------------------
__global__ __launch_bounds__(256, 2) void xpre_kernel(
    const float* __restrict__ x, const float* __restrict__ x2h,
    float* __restrict__ out)
{
  __shared__ float xl[64 * N_INP];            // 32 KB: 64 timesteps of x
  const int tb = blockIdx.x;                  // timestep block (64 steps)
  const int n  = blockIdx.y;                  // module
  const int t  = threadIdx.x;                 // h index 0..255

  const float4* xs  = (const float4*)(x + (size_t)tb * 64 * N_INP);
  float4*       xld = (float4*)xl;
  for (int k = t; k < 64 * N_INP / 4; k += 256) xld[k] = xs[k];

  float w[N_INP];                             // x2h[n, h=t, :] in VGPRs
  const float* wrow = x2h + ((size_t)n * N_HID + t) * N_INP;
#pragma unroll
  for (int j = 0; j < N_INP; j += 4) {
    const float4 a = *(const float4*)(wrow + j);
    w[j] = a.x; w[j+1] = a.y; w[j+2] = a.z; w[j+3] = a.w;
  }
  __syncthreads();

  for (int tt = 0; tt < 64; ++tt) {
    float a0=0.f, a1=0.f, a2=0.f, a3=0.f;
#pragma unroll
    for (int j = 0; j < N_INP; j += 4) {
      const float4 h4 = *(const float4*)&xl[tt * N_INP + j];
      a0 = fmaf(w[j],   h4.x, a0);
      a1 = fmaf(w[j+1], h4.y, a1);
      a2 = fmaf(w[j+2], h4.z, a2);
      a3 = fmaf(w[j+3], h4.w, a3);
    }
    out[((size_t)(tb*64 + tt) * N_MOD + n) * N_HID + t] = (a0+a1)+(a2+a3);
  }
}

// --------------------------------------------------------------------------
// Persistent stepping kernel: 64 WGs x 512 threads, one WG per module.
// Thread t: row h = t&255, column chunk c = t>>8 (two 128-col chunks).
// wv = wm[h, c*128:+128] is VGPR-resident (publish critical path).
// wh = h2h[m,h,c*128:+128] streams from L2 each step (off critical path).
//
// Steady state, step s:
//   ph1: issue xpre load; stream wh + r-partials -> redr
//   ph2: (s>0) relaxed-poll 64 flags >= s; barrier; acquire fence;
//        gather fb = sum_m' conn[m,m'] * v_s[m',h]   (v_s in vbuf[s&1])
//   ph3: update hy,hz (tanh Euler); hy -> LDS; barrier
//   ph4: v_{s+1}-partials -> redv; barrier; publish v_{s+1} -> vbuf[(s+1)&1];
//        barrier (drains publishes); t==0: flag[m] = s+1 (release)
//   ph5: write states_seq[s+1], fb_seq[s]  (after flag: off critical path)
// Buffer-reuse safety: WG overwrites vbuf[p] for v_{s+1} only after passing
// poll(s), which proves every WG finished its step-(s-1) gather of vbuf[p].
// --------------------------------------------------------------------------
__global__ __launch_bounds__(512, 2) void archnet_step(
    const float* __restrict__ init, const float* __restrict__ wm,
    const float* __restrict__ conn, const float* __restrict__ h2h,
    const float* __restrict__ bias,
    float* __restrict__ out_states, float* __restrict__ out_fb,
    float* vbuf, unsigned* flags)
{
  const int m = blockIdx.x;         // 0..63
  const int t = threadIdx.x;        // 0..511
  const int h = t & 255;
  const int c = t >> 8;             // 0 or 1

  __shared__ float hy[N_HID];
  __shared__ float redv[512];
  __shared__ float redr[512];
  __shared__ float connrow[N_MOD];

  // ---- resident feedback weights: wm[h, c*128 .. +128) ----
  float wv[128];
  {
    const float* wp = wm + (size_t)h * N_HID + c * 128;
#pragma unroll
    for (int j = 0; j < 128; j += 4) {
      const float4 a = *(const float4*)(wp + j);
      wv[j] = a.x; wv[j+1] = a.y; wv[j+2] = a.z; wv[j+3] = a.w;
    }
  }

  // ---- init ----
  float biasv = 0.f, hzv = 0.f;
  if (t < N_HID) {
    hy[t] = init[(size_t)m * 512 + t];
    biasv = bias[(size_t)m * N_HID + h];
    hzv   = init[(size_t)m * 512 + 256 + h];
    out_states[(size_t)m * 512 + h]       = init[(size_t)m * 512 + h];
    out_states[(size_t)m * 512 + 256 + h] = hzv;
  }
  if (t < N_MOD) connrow[t] = conn[m * N_MOD + t];
  __syncthreads();

  const float* whbase = h2h + ((size_t)m * N_HID + h) * N_HID + c * 128;

  for (int s = 0; s < T_STEPS; ++s) {
    // ---- ph1: xpre + streamed h2h row-chunk -> r partial ----
    float xq = 0.f;
    if (t < N_HID) xq = out_fb[((size_t)s * N_MOD + m) * N_HID + h];
    {
      float b0=0.f, b1=0.f, b2=0.f, b3=0.f;
#pragma unroll
      for (int j = 0; j < 128; j += 4) {
        const float4 a  = *(const float4*)(whbase + j);
        const float4 h4 = *(const float4*)&hy[c*128 + j];
        b0 = fmaf(a.x, h4.x, b0);
        b1 = fmaf(a.y, h4.y, b1);
        b2 = fmaf(a.z, h4.z, b2);
        b3 = fmaf(a.w, h4.w, b3);
      }
      redr[t] = (b0+b1)+(b2+b3);
    }

    // ---- ph2: poll + gather ----
    float fb = 0.f;
    if (s > 0) {
      if (t < N_MOD) {
        while (AG_LD(&flags[t]) < (unsigned)s) { }   // relaxed poll
      }
    }
    __syncthreads();             // poll done AND redr complete
    if (s > 0) {
      __builtin_amdgcn_fence(__ATOMIC_ACQUIRE, "agent");
      if (t < N_HID) {
        const float* vb = vbuf + (size_t)(s & 1) * (N_MOD * N_HID);
        float f0=0.f, f1=0.f, f2=0.f, f3=0.f;
#pragma unroll
        for (int mp = 0; mp < N_MOD; mp += 4) {
          const float v0 = AG_LD(&vb[(size_t)(mp+0) * N_HID + h]);
          const float v1 = AG_LD(&vb[(size_t)(mp+1) * N_HID + h]);
          const float v2 = AG_LD(&vb[(size_t)(mp+2) * N_HID + h]);
          const float v3 = AG_LD(&vb[(size_t)(mp+3) * N_HID + h]);
          f0 = fmaf(connrow[mp+0], v0, f0);
          f1 = fmaf(connrow[mp+1], v1, f1);
          f2 = fmaf(connrow[mp+2], v2, f2);
          f3 = fmaf(connrow[mp+3], v3, f3);
        }
        fb = (f0+f1)+(f2+f3);
      }
    }

    // ---- ph3: update ----
    float hyn = 0.f;
    if (t < N_HID) {
      const float r   = redr[h] + redr[h + 256];
      const float pre = xq + r + biasv + fb;
      const float th  = tanhf(pre);
      const float hyo = hy[h];
      const float hzn = hzv + 0.01f * (th - hyo - hzv);   // GAMMA=EPS=1, DT=0.01
      hyn = hyo + 0.01f * hzn;
      hzv = hzn;
      hy[h] = hyn;               // only this thread read hy[h] since last barrier
    }
    __syncthreads();             // hy_{s+1} visible to all

    // ---- ph4: v_{s+1} partial, publish, flag ----
    {
      float a0=0.f, a1=0.f, a2=0.f, a3=0.f;
#pragma unroll
      for (int j = 0; j < 128; j += 4) {
        const float4 h4 = *(const float4*)&hy[c*128 + j];
        a0 = fmaf(wv[j],   h4.x, a0);
        a1 = fmaf(wv[j+1], h4.y, a1);
        a2 = fmaf(wv[j+2], h4.z, a2);
        a3 = fmaf(wv[j+3], h4.w, a3);
      }
      redv[t] = (a0+a1)+(a2+a3);
    }
    __syncthreads();
    {
      float* vbn = vbuf + (size_t)((s + 1) & 1) * (N_MOD * N_HID);
      if (t < N_HID) AG_ST(&vbn[m * N_HID + h], redv[h] + redv[h + 256]);
    }
    __syncthreads();             // drains publishes (vmcnt 0 per wave)
    if (t == 0) AG_ST_REL(&flags[m], (unsigned)(s + 1));

    // ---- ph5: outputs (off critical path) ----
    if (t < N_HID) {
      const size_t ob = ((size_t)(s + 1) * N_MOD + m) * 512;
      out_states[ob + h]       = hyn;
      out_states[ob + 256 + h] = hzv;
      out_fb[((size_t)s * N_MOD + m) * N_HID + h] = fb;   // overwrite xpre
    }
  }
}

// --------------------------------------------------------------------------
extern "C" void kernel_launch(void* const* d_in, const int* in_sizes, int n_in,
                              void* d_out, int out_size, void* d_ws, size_t ws_size,
                              hipStream_t stream) {
  const float* x    = (const float*)d_in[0];   // (2048,128)
  const float* init = (const float*)d_in[1];   // (64,2,256)
  const float* wmw  = (const float*)d_in[2];   // (256,256)
  const float* conn = (const float*)d_in[3];   // (64,64)
  const float* x2h  = (const float*)d_in[4];   // (64,256,128)
  const float* h2h  = (const float*)d_in[5];   // (64,256,256)
  const float* bias = (const float*)d_in[6];   // (64,256)

  float* out_states = (float*)d_out;                                        // (2049,64,2,256)
  float* out_fb     = out_states + (size_t)(T_STEPS+1) * N_MOD * 2 * N_HID; // (2048,64,256)

  // workspace layout: flags (64 u32) | v double-buffer (2*64*256 f32)
  unsigned* flags = (unsigned*)d_ws;
  float*    vbuf  = (float*)((char*)d_ws + 256);
  hipMemsetAsync(d_ws, 0, 256, stream);        // flags must start at 0 each call

  xpre_kernel<<<dim3(T_STEPS/64, N_MOD), dim3(256), 0, stream>>>(x, x2h, out_fb);

  void* args[] = {
    (void*)&init, (void*)&wmw, (void*)&conn, (void*)&h2h, (void*)&bias,
    (void*)&out_states, (void*)&out_fb, (void*)&vbuf, (void*)&flags
  };
  hipLaunchCooperativeKernel((void*)archnet_step, dim3(64), dim3(512),
                             args, 0, stream);
}